// Round 7
// baseline (2015.943 us; speedup 1.0000x reference)
//
#include <hip/hip_runtime.h>

// NeuralODE: B=1024, D=64, F=8, H=256, 196 substeps x 6 dopri5 stages.
// R7: MFMA path. 64 blocks x 256 threads (4 waves), 16 batch rows/block.
// Precision: split-f16 (Ootomo): v = hi + lo (both f16); A.B via
// hi.hi + hi.lo + lo.hi -> ~2^-22 rel product error (fp32-class), since
// plain f16 (3e-4/eval) x ODE error amplification risks the 0.105 threshold.
// GEMM1 (z[16x96] @ W1[96x256]): wave wv owns N-tiles wv*4..wv*4+3,
//   B-frags in regs (96 regs), K padded 72->96 with zeros (LDS z pad zeroed).
// GEMM2 (h[16x256] @ W2[256x64]): wave wv owns N-tile wv (64 B-frag regs).
// State x, k1..k6 live in C/D-layout registers per lane:
//   elem [row=lq*4+r][col=wv*16+lm] -> Butcher algebra all in-register.
// MFMA layouts (m89/m91-verified): A[m=l&15][k=(l>>4)*8+j],
//   B[k=(l>>4)*8+j][n=l&15], D[row=(l>>4)*4+reg][col=l&15].
// waves_per_eu(1,1): 512-reg budget; AGPR parking harmless (MFMA reads AGPR).

typedef _Float16 half8 __attribute__((ext_vector_type(8)));
typedef float f32x4 __attribute__((ext_vector_type(4)));

#define MFMA16(a, b, c) __builtin_amdgcn_mfma_f32_16x16x32_f16((a), (b), (c), 0, 0, 0)

__device__ __forceinline__ float fast_tanh(float x) {
    float e = __expf(2.0f * x);
    return 1.0f - 2.0f / (e + 1.0f);   // saturates correctly, ~1e-6 abs err
}

__global__ __attribute__((amdgpu_waves_per_eu(1, 1))) __launch_bounds__(256)
void node_kernel(const float* __restrict__ x0,
                 const float* __restrict__ t_eval,
                 const float* __restrict__ t_u,
                 const float* __restrict__ u_batch,
                 const float* __restrict__ W1,
                 const float* __restrict__ b1,
                 const float* __restrict__ W2,
                 const float* __restrict__ b2,
                 float* __restrict__ out)
{
    // z: 16 x 96 (K-pad), stride 104 halves (208 B = 13x16: aligned, 2-way banks)
    // h: 16 x 256, stride 264 halves (528 B = 33x16: aligned, 2-way banks)
    __shared__ __align__(16) _Float16 zh[16][104];
    __shared__ __align__(16) _Float16 zl[16][104];
    __shared__ __align__(16) _Float16 hh[16][264];
    __shared__ __align__(16) _Float16 hl[16][264];
    __shared__ __align__(16) float ush[6][16][8];   // interp u, fp32

    const int tid = threadIdx.x;
    const int l   = tid & 63;
    const int wv  = tid >> 6;        // wave 0..3
    const int lm  = l & 15;          // m (A) / n (B,D) index
    const int lq  = l >> 4;          // quad
    const int blk = blockIdx.x;
    const int n2  = wv * 16 + lm;    // this lane's GEMM2 output col (state dim)

    // --- zero the z K-pad (cols 72..103) once; never written again ---
    {
        const int row = tid >> 4, cp = tid & 15;
        *(uint32_t*)&zh[row][72 + cp * 2] = 0u;
        *(uint32_t*)&zl[row][72 + cp * 2] = 0u;
    }

    // --- B-fragments (split hi/lo), one-time loads ---
    half8 b1h[4][3], b1l[4][3];
#pragma unroll
    for (int t = 0; t < 4; ++t) {
        const int n1 = (wv * 4 + t) * 16 + lm;
#pragma unroll
        for (int c = 0; c < 3; ++c) {
#pragma unroll
            for (int j = 0; j < 8; ++j) {
                const int k = c * 32 + lq * 8 + j;
                const float v = (k < 72) ? W1[k * 256 + n1] : 0.0f;
                const _Float16 hi = (_Float16)v;
                b1h[t][c][j] = hi;
                b1l[t][c][j] = (_Float16)(v - (float)hi);
            }
        }
    }
    half8 b2h[8], b2l[8];
#pragma unroll
    for (int c = 0; c < 8; ++c) {
#pragma unroll
        for (int j = 0; j < 8; ++j) {
            const int k = c * 32 + lq * 8 + j;
            const float v = W2[k * 64 + n2];
            const _Float16 hi = (_Float16)v;
            b2h[c][j] = hi;
            b2l[c][j] = (_Float16)(v - (float)hi);
        }
    }
    float b1b[4];
#pragma unroll
    for (int t = 0; t < 4; ++t) b1b[t] = b1[(wv * 4 + t) * 16 + lm];
    const float b2b = b2[n2];

    // --- ODE state in C/D-layout registers: elem [lq*4+r][n2] ---
    float xr[4];
    float kfr[6][4];
#pragma unroll
    for (int r = 0; r < 4; ++r) {
        const int gr = blk * 16 + lq * 4 + r;
        xr[r] = x0[gr * 64 + n2];
        out[gr * 3200 + n2] = xr[r];      // t_eval[0]
    }
    __syncthreads();   // pad-zero visible

#pragma unroll 1
    for (int step = 0; step < 196; ++step) {
        const int n = step >> 2;
        const int m = step & 3;
        const float te0 = t_eval[n];
        const float dtc = t_eval[n + 1] - te0;
        const float t   = te0 + dtc * (0.25f * (float)m);
        const float dt  = dtc * 0.25f;

        // --- u prefetch+interp: 6 stages x 16 rows x 8 feats = 768 slots ---
        // (no barrier needed: s=0 slots are written and read by the same
        //  thread; s>=1 reads are separated by stage barriers; previous-step
        //  stage-5 reads are behind 2 barriers)
#pragma unroll
        for (int ii = 0; ii < 3; ++ii) {
            const int idx = tid + ii * 256;
            const int s   = idx >> 7;           // wave-uniform per (wave, ii)
            const int rem = idx & 127;
            const int mr  = rem >> 3, f = rem & 7;
            float cs;
            switch (s) {
                case 0: cs = 0.0f; break;
                case 1: cs = 1.0f / 5.0f; break;
                case 2: cs = 3.0f / 10.0f; break;
                case 3: cs = 4.0f / 5.0f; break;
                case 4: cs = 8.0f / 9.0f; break;
                default: cs = 1.0f; break;
            }
            const float tsv = t + dt * cs;
            int iu = (int)(tsv * 127.0f);       // == searchsorted-1 (gap >> eps)
            iu = iu < 0 ? 0 : (iu > 126 ? 126 : iu);
            const float ta = t_u[iu];
            const float tb = t_u[iu + 1];
            const float wt = (tsv - ta) / (tb - ta);
            const float* ub = &u_batch[(blk * 16 + mr) * 1024 + iu * 8 + f];
            const float u0v = ub[0];
            const float u1v = ub[8];
            ush[s][mr][f] = fmaf(wt, u1v - u0v, u0v);
        }

#pragma unroll
        for (int s = 0; s < 6; ++s) {
            // --- stage state xs (fp32, in-register Butcher combos) ---
            float xs[4];
#pragma unroll
            for (int r = 0; r < 4; ++r) {
                float v;
                if (s == 0)      v = xr[r];
                else if (s == 1) v = fmaf(dt, kfr[0][r] * (1.0f/5.0f), xr[r]);
                else if (s == 2) v = fmaf(dt, fmaf(3.0f/40.0f, kfr[0][r], (9.0f/40.0f)*kfr[1][r]), xr[r]);
                else if (s == 3) v = fmaf(dt, (44.0f/45.0f)*kfr[0][r] + (-56.0f/15.0f)*kfr[1][r]
                                             + (32.0f/9.0f)*kfr[2][r], xr[r]);
                else if (s == 4) v = fmaf(dt, (19372.0f/6561.0f)*kfr[0][r] + (-25360.0f/2187.0f)*kfr[1][r]
                                             + (64448.0f/6561.0f)*kfr[2][r] + (-212.0f/729.0f)*kfr[3][r], xr[r]);
                else             v = fmaf(dt, (9017.0f/3168.0f)*kfr[0][r] + (-355.0f/33.0f)*kfr[1][r]
                                             + (46732.0f/5247.0f)*kfr[2][r] + (49.0f/176.0f)*kfr[3][r]
                                             + (-5103.0f/18656.0f)*kfr[4][r], xr[r]);
                xs[r] = v;
            }
            // write z x-part (split): rows lq*4+r, col n2
#pragma unroll
            for (int r = 0; r < 4; ++r) {
                const _Float16 hi = (_Float16)xs[r];
                zh[lq * 4 + r][n2] = hi;
                zl[lq * 4 + r][n2] = (_Float16)(xs[r] - (float)hi);
            }
            // write z u-part (cols 64..71), threads 0..127 (waves 0,1)
            if (tid < 128) {
                const int mr = tid >> 3, f = tid & 7;
                const float uv = ush[s][mr][f];
                const _Float16 hi = (_Float16)uv;
                zh[mr][64 + f] = hi;
                zl[mr][64 + f] = (_Float16)(uv - (float)hi);
            }
            __syncthreads();

            // --- GEMM1: h_pre = z @ W1 ; A-frags from LDS ---
            half8 azh[3], azl[3];
#pragma unroll
            for (int c = 0; c < 3; ++c) {
                azh[c] = *(const half8*)&zh[lm][c * 32 + lq * 8];
                azl[c] = *(const half8*)&zl[lm][c * 32 + lq * 8];
            }
#pragma unroll
            for (int t = 0; t < 4; ++t) {
                f32x4 acc = {0.0f, 0.0f, 0.0f, 0.0f};
#pragma unroll
                for (int c = 0; c < 3; ++c) {
                    acc = MFMA16(azh[c], b1h[t][c], acc);
                    acc = MFMA16(azh[c], b1l[t][c], acc);
                    acc = MFMA16(azl[c], b1h[t][c], acc);
                }
                // tanh + split-store h
#pragma unroll
                for (int r = 0; r < 4; ++r) {
                    const float hv = fast_tanh(acc[r] + b1b[t]);
                    const _Float16 hi = (_Float16)hv;
                    hh[lq * 4 + r][(wv * 4 + t) * 16 + lm] = hi;
                    hl[lq * 4 + r][(wv * 4 + t) * 16 + lm] = (_Float16)(hv - (float)hi);
                }
            }
            __syncthreads();

            // --- GEMM2: k = h @ W2 (+b2); 2 accumulators to halve chain ---
            f32x4 accA = {0.0f, 0.0f, 0.0f, 0.0f};
            f32x4 accB = {0.0f, 0.0f, 0.0f, 0.0f};
#pragma unroll
            for (int c = 0; c < 8; ++c) {
                const half8 ah = *(const half8*)&hh[lm][c * 32 + lq * 8];
                const half8 al = *(const half8*)&hl[lm][c * 32 + lq * 8];
                if (c & 1) {
                    accB = MFMA16(ah, b2h[c], accB);
                    accB = MFMA16(ah, b2l[c], accB);
                    accB = MFMA16(al, b2h[c], accB);
                } else {
                    accA = MFMA16(ah, b2h[c], accA);
                    accA = MFMA16(ah, b2l[c], accA);
                    accA = MFMA16(al, b2h[c], accA);
                }
            }
#pragma unroll
            for (int r = 0; r < 4; ++r) kfr[s][r] = accA[r] + accB[r] + b2b;
        }

        // --- dopri5 update (in-register) + output every 4th substep ---
#pragma unroll
        for (int r = 0; r < 4; ++r) {
            xr[r] = fmaf(dt, (35.0f/384.0f)*kfr[0][r] + (500.0f/1113.0f)*kfr[2][r]
                            + (125.0f/192.0f)*kfr[3][r] + (-2187.0f/6784.0f)*kfr[4][r]
                            + (11.0f/84.0f)*kfr[5][r], xr[r]);
        }
        if (m == 3) {
#pragma unroll
            for (int r = 0; r < 4; ++r)
                out[(blk * 16 + lq * 4 + r) * 3200 + (n + 1) * 64 + n2] = xr[r];
        }
    }
}

extern "C" void kernel_launch(void* const* d_in, const int* in_sizes, int n_in,
                              void* d_out, int out_size, void* d_ws, size_t ws_size,
                              hipStream_t stream) {
    const float* x0      = (const float*)d_in[0];
    const float* t_eval  = (const float*)d_in[1];
    const float* t_u     = (const float*)d_in[2];
    const float* u_batch = (const float*)d_in[3];
    const float* W1      = (const float*)d_in[4];
    const float* b1      = (const float*)d_in[5];
    const float* W2      = (const float*)d_in[6];
    const float* b2      = (const float*)d_in[7];
    float* out = (float*)d_out;

    node_kernel<<<dim3(64), dim3(256), 0, stream>>>(
        x0, t_eval, t_u, u_batch, W1, b1, W2, b2, out);
}

// Round 8
// 1734.705 us; speedup vs baseline: 1.1621x; 1.1621x over previous
//
#include <hip/hip_runtime.h>

// NeuralODE: B=1024, D=64, F=8, H=256, 196 substeps x 6 dopri5 stages.
// R8: MFMA path, 64 blocks x 512 threads (8 waves, 2/SIMD), 16 rows/block.
// R7 post-mortem: 1 wave/SIMD exposed all latency; row-major h LDS gave
// 8-way bank conflicts (2.65e7). Fixes:
//  - fragment-order LDS: zA/hA stored as A-frag planes [kq][m][8] halves,
//    plane stride 144 halves (288B) -> wave b128 frag reads are balanced
//    8-dword-per-bank (floor), zero excess conflict; transpose cost moved
//    to a few 4-way u16 writes.
//  - GEMM1 (z[16x96]@W1): 3-term split-f16 (Ootomo), wave owns 2 N-tiles.
//  - GEMM2 (h[16x256]@W2): 2-term (AhBh+AhBl; h-residual dropped, h in
//    [-1,1] so error ~2e-4 abs in k), wave (nt,kh) owns N-tile x K-half,
//    f32 partials reduced via LDS red[] (b128-aligned, padded rows).
// State x,k in C/D-layout regs of waves 0-3 (wave nt owns dims nt*16+lm).
// MFMA layouts (HW-verified via R7 pass): A[m=l&15][k=(l>>4)*8+j],
//   B[k=(l>>4)*8+j][n=l&15], D[row=(l>>4)*4+reg][col=l&15].

typedef _Float16 half8 __attribute__((ext_vector_type(8)));
typedef float f32x4 __attribute__((ext_vector_type(4)));

#define MFMA16(a, b, c) __builtin_amdgcn_mfma_f32_16x16x32_f16((a), (b), (c), 0, 0, 0)

__device__ __forceinline__ float fast_tanh(float x) {
    float e = __expf(2.0f * x);
    return 1.0f - 2.0f / (e + 1.0f);   // saturates correctly, ~1e-6 abs err
}

__global__ __attribute__((amdgpu_waves_per_eu(2, 2))) __launch_bounds__(512)
void node_kernel(const float* __restrict__ x0,
                 const float* __restrict__ t_eval,
                 const float* __restrict__ t_u,
                 const float* __restrict__ u_batch,
                 const float* __restrict__ W1,
                 const float* __restrict__ b1,
                 const float* __restrict__ W2,
                 const float* __restrict__ b2,
                 float* __restrict__ out)
{
    // A-fragment planes: elem (m,k) at [ (k>>3)*144 + m*8 + (k&7) ]
    __shared__ __align__(16) _Float16 zAh[12 * 144];   // K=96 (72 real + pad)
    __shared__ __align__(16) _Float16 zAl[12 * 144];
    __shared__ __align__(16) _Float16 hAh[32 * 144];   // K=256, hi only
    __shared__ __align__(16) float red[8][16][20];     // [nt*2+kh][col lm][row+pad]
    __shared__ __align__(16) float ush[6][16][8];      // interp u per stage/row

    const int tid = threadIdx.x;
    const int wv  = tid >> 6;        // wave 0..7
    const int l   = tid & 63;
    const int lm  = l & 15;
    const int lq  = l >> 4;
    const int blk = blockIdx.x;

    // --- zero the z K-pad planes (kq=9..11, k=72..95) once ---
    if (tid < 192) {
        const int kq = 9 + (tid >> 6);
        const int e2 = (tid & 63) * 2;
        *(uint32_t*)&zAh[kq * 144 + e2] = 0u;
        *(uint32_t*)&zAl[kq * 144 + e2] = 0u;
    }

    // --- GEMM1 B-frags: wave owns N-tiles wv*2, wv*2+1 (split hi/lo) ---
    half8 b1h[2][3], b1l[2][3];
    float b1b[2];
#pragma unroll
    for (int t2 = 0; t2 < 2; ++t2) {
        const int n1 = (wv * 2 + t2) * 16 + lm;
        b1b[t2] = b1[n1];
#pragma unroll
        for (int c = 0; c < 3; ++c) {
#pragma unroll
            for (int j = 0; j < 8; ++j) {
                const int k = c * 32 + lq * 8 + j;
                const float v = (k < 72) ? W1[k * 256 + n1] : 0.0f;
                const _Float16 hi = (_Float16)v;
                b1h[t2][c][j] = hi;
                b1l[t2][c][j] = (_Float16)(v - (float)hi);
            }
        }
    }

    // --- GEMM2 task (nt = wv&3, kh = wv>>2): B-frags for K-half kh ---
    const int nt = wv & 3;
    const int kh = wv >> 2;
    const int n2 = nt * 16 + lm;
    half8 b2h[4], b2l[4];
#pragma unroll
    for (int cc = 0; cc < 4; ++cc) {
#pragma unroll
        for (int j = 0; j < 8; ++j) {
            const int k = kh * 128 + cc * 32 + lq * 8 + j;
            const float v = W2[k * 64 + n2];
            const _Float16 hi = (_Float16)v;
            b2h[cc][j] = hi;
            b2l[cc][j] = (_Float16)(v - (float)hi);
        }
    }
    const float b2b = b2[n2];

    // --- ODE state: wave nt (wv<4) owns dims nt*16+lm, rows lq*4+r ---
    const bool is_st = (wv < 4);
    float xr[4];
    float kfr[5][4];
    if (is_st) {
#pragma unroll
        for (int r = 0; r < 4; ++r) {
            const int gr = blk * 16 + lq * 4 + r;
            xr[r] = x0[gr * 64 + n2];
            out[gr * 3200 + n2] = xr[r];      // t_eval[0]
        }
    }
    __syncthreads();   // pad zeros visible

#pragma unroll 1
    for (int step = 0; step < 196; ++step) {
        const int n = step >> 2;
        const int m = step & 3;
        const float te0 = t_eval[n];
        const float dtc = t_eval[n + 1] - te0;
        const float t   = te0 + dtc * (0.25f * (float)m);
        const float dt  = dtc * 0.25f;

        // --- u prefetch+interp: 768 slots (6 stages x 16 rows x 8 feats) ---
#pragma unroll
        for (int ii = 0; ii < 2; ++ii) {
            const int slot = tid + ii * 512;
            if (ii == 0 || tid < 256) {
                const int s   = slot >> 7;          // wave-uniform
                const int rem = slot & 127;
                const int mr  = rem >> 3, f = rem & 7;
                float cs;
                switch (s) {
                    case 0: cs = 0.0f; break;
                    case 1: cs = 1.0f / 5.0f; break;
                    case 2: cs = 3.0f / 10.0f; break;
                    case 3: cs = 4.0f / 5.0f; break;
                    case 4: cs = 8.0f / 9.0f; break;
                    default: cs = 1.0f; break;
                }
                const float tsv = t + dt * cs;
                int iu = (int)(tsv * 127.0f);       // == searchsorted-1
                iu = iu < 0 ? 0 : (iu > 126 ? 126 : iu);
                const float ta = t_u[iu];
                const float tb = t_u[iu + 1];
                const float wt = (tsv - ta) / (tb - ta);
                const float* ub = &u_batch[(blk * 16 + mr) * 1024 + iu * 8 + f];
                const float u0v = ub[0];
                const float u1v = ub[8];
                ush[s][mr][f] = fmaf(wt, u1v - u0v, u0v);
            }
        }
        __syncthreads();   // B0: ush ready

#pragma unroll
        for (int s = 0; s < 6; ++s) {
            // --- state waves publish z x-part (dims n2, rows lq*4+r) ---
            if (is_st) {
#pragma unroll
                for (int r = 0; r < 4; ++r) {
                    float v;
                    if (s == 0)      v = xr[r];
                    else if (s == 1) v = fmaf(dt, kfr[0][r] * (1.0f/5.0f), xr[r]);
                    else if (s == 2) v = fmaf(dt, fmaf(3.0f/40.0f, kfr[0][r], (9.0f/40.0f)*kfr[1][r]), xr[r]);
                    else if (s == 3) v = fmaf(dt, (44.0f/45.0f)*kfr[0][r] + (-56.0f/15.0f)*kfr[1][r]
                                                 + (32.0f/9.0f)*kfr[2][r], xr[r]);
                    else if (s == 4) v = fmaf(dt, (19372.0f/6561.0f)*kfr[0][r] + (-25360.0f/2187.0f)*kfr[1][r]
                                                 + (64448.0f/6561.0f)*kfr[2][r] + (-212.0f/729.0f)*kfr[3][r], xr[r]);
                    else             v = fmaf(dt, (9017.0f/3168.0f)*kfr[0][r] + (-355.0f/33.0f)*kfr[1][r]
                                                 + (46732.0f/5247.0f)*kfr[2][r] + (49.0f/176.0f)*kfr[3][r]
                                                 + (-5103.0f/18656.0f)*kfr[4][r], xr[r]);
                    const _Float16 hi = (_Float16)v;
                    const int a = (n2 >> 3) * 144 + (lq * 4 + r) * 8 + (n2 & 7);
                    zAh[a] = hi;
                    zAl[a] = (_Float16)(v - (float)hi);
                }
            }
            // --- wave 4 publishes z u-part (k=64..71 -> plane kq=8) ---
            if (wv == 4) {
#pragma unroll
                for (int h2 = 0; h2 < 2; ++h2) {
                    const int mm = (l >> 3) + h2 * 8;
                    const int f  = l & 7;
                    const float uv = ush[s][mm][f];
                    const _Float16 hi = (_Float16)uv;
                    zAh[8 * 144 + mm * 8 + f] = hi;
                    zAl[8 * 144 + mm * 8 + f] = (_Float16)(uv - (float)hi);
                }
            }
            __syncthreads();   // B1: z ready

            // --- GEMM1: read A-frags once, 2 N-tiles, 3-term split ---
            half8 azh[3], azl[3];
#pragma unroll
            for (int c = 0; c < 3; ++c) {
                azh[c] = *(const half8*)&zAh[(c * 4 + lq) * 144 + lm * 8];
                azl[c] = *(const half8*)&zAl[(c * 4 + lq) * 144 + lm * 8];
            }
#pragma unroll
            for (int t2 = 0; t2 < 2; ++t2) {
                f32x4 aHH = {0.f, 0.f, 0.f, 0.f};
                f32x4 aHL = {0.f, 0.f, 0.f, 0.f};
                f32x4 aLH = {0.f, 0.f, 0.f, 0.f};
#pragma unroll
                for (int c = 0; c < 3; ++c) {
                    aHH = MFMA16(azh[c], b1h[t2][c], aHH);
                    aHL = MFMA16(azh[c], b1l[t2][c], aHL);
                    aLH = MFMA16(azl[c], b1h[t2][c], aLH);
                }
                const int kqb = (wv * 2 + t2) * 2 + (lm >> 3);   // h-col>>3
#pragma unroll
                for (int r = 0; r < 4; ++r) {
                    const float hv = fast_tanh(aHH[r] + aHL[r] + aLH[r] + b1b[t2]);
                    hAh[kqb * 144 + (lq * 4 + r) * 8 + (lm & 7)] = (_Float16)hv;
                }
            }
            __syncthreads();   // B2: h ready

            // --- GEMM2: task (nt, kh), 2-term split, f32 partial to red ---
            f32x4 aP = {0.f, 0.f, 0.f, 0.f};
            f32x4 aQ = {0.f, 0.f, 0.f, 0.f};
#pragma unroll
            for (int cc = 0; cc < 4; ++cc) {
                const half8 ah = *(const half8*)&hAh[(kh * 16 + cc * 4 + lq) * 144 + lm * 8];
                aP = MFMA16(ah, b2h[cc], aP);
                aQ = MFMA16(ah, b2l[cc], aQ);
            }
            const f32x4 psum = aP + aQ;
            *(f32x4*)&red[(nt << 1) + kh][lm][lq * 4] = psum;
            __syncthreads();   // B3: partials ready

            // --- state waves: reduce 2 K-halves -> k_s ---
            if (is_st) {
                const f32x4 pa = *(const f32x4*)&red[nt << 1][lm][lq * 4];
                const f32x4 pb = *(const f32x4*)&red[(nt << 1) + 1][lm][lq * 4];
                if (s < 5) {
#pragma unroll
                    for (int r = 0; r < 4; ++r) kfr[s][r] = pa[r] + pb[r] + b2b;
                } else {
#pragma unroll
                    for (int r = 0; r < 4; ++r) {
                        const float k6 = pa[r] + pb[r] + b2b;
                        xr[r] = fmaf(dt, (35.0f/384.0f)*kfr[0][r] + (500.0f/1113.0f)*kfr[2][r]
                                        + (125.0f/192.0f)*kfr[3][r] + (-2187.0f/6784.0f)*kfr[4][r]
                                        + (11.0f/84.0f)*k6, xr[r]);
                    }
                }
            }
        }

        // --- output every 4th substep ---
        if (is_st && m == 3) {
#pragma unroll
            for (int r = 0; r < 4; ++r)
                out[(blk * 16 + lq * 4 + r) * 3200 + (n + 1) * 64 + n2] = xr[r];
        }
    }
}

extern "C" void kernel_launch(void* const* d_in, const int* in_sizes, int n_in,
                              void* d_out, int out_size, void* d_ws, size_t ws_size,
                              hipStream_t stream) {
    const float* x0      = (const float*)d_in[0];
    const float* t_eval  = (const float*)d_in[1];
    const float* t_u     = (const float*)d_in[2];
    const float* u_batch = (const float*)d_in[3];
    const float* W1      = (const float*)d_in[4];
    const float* b1      = (const float*)d_in[5];
    const float* W2      = (const float*)d_in[6];
    const float* b2      = (const float*)d_in[7];
    float* out = (float*)d_out;

    node_kernel<<<dim3(64), dim3(512), 0, stream>>>(
        x0, t_eval, t_u, u_batch, W1, b1, W2, b2, out);
}

// Round 9
// 1594.546 us; speedup vs baseline: 1.2643x; 1.0879x over previous
//
#include <hip/hip_runtime.h>

// NeuralODE: B=1024, D=64, F=8, H=256, 196 substeps x 6 dopri5 stages.
// R9: MFMA path, 64 blocks x 1024 threads (16 waves, 4/SIMD), 16 rows/block.
// R8 post-mortem: stage=3540cyc with pipes ~20% busy -> latency-bound at
// 2 waves/SIMD. R9: 4 waves/SIMD, finer tasks, leaner precision:
//  - GEMM1 (z[16x96]@W1): 2-term split (z-hi.W1-hi + z-hi.W1-lo); z-residual
//    dropped (z ~O(1), error ~1e-3 in h, far under 0.105 threshold with the
//    observed 0.0156 floor). Wave owns 1 N-tile: 3 b128 A-reads, 6 MFMAs.
//  - GEMM2 (h[16x256]@W2): 2-term, wave (nt=wv&3, kq=wv>>2) owns N-tile x
//    K-quarter: 2 b128 reads, 4 MFMAs; 4-way partial reduce via red[].
// State x,k in C/D regs of waves 0-3 (wave nt owns cols nt*16+lm).
// A-frag LDS planes [k>>3][m][k&7], stride 144 halves (288B): b128 frag
// reads are 8-access/bank balanced (floor). u-part z-writes dword-packed.
// MFMA layouts (HW-verified R7/R8 pass): A[m=l&15][k=(l>>4)*8+j],
//   B[k=(l>>4)*8+j][n=l&15], D[row=(l>>4)*4+reg][col=l&15].

typedef _Float16 half8 __attribute__((ext_vector_type(8)));
typedef float f32x4 __attribute__((ext_vector_type(4)));

#define MFMA16(a, b, c) __builtin_amdgcn_mfma_f32_16x16x32_f16((a), (b), (c), 0, 0, 0)

__device__ __forceinline__ float fast_tanh(float x) {
    float e = __expf(2.0f * x);
    return 1.0f - 2.0f / (e + 1.0f);   // saturates correctly, ~1e-6 abs err
}

__global__ __attribute__((amdgpu_waves_per_eu(4, 4))) __launch_bounds__(1024)
void node_kernel(const float* __restrict__ x0,
                 const float* __restrict__ t_eval,
                 const float* __restrict__ t_u,
                 const float* __restrict__ u_batch,
                 const float* __restrict__ W1,
                 const float* __restrict__ b1,
                 const float* __restrict__ W2,
                 const float* __restrict__ b2,
                 float* __restrict__ out)
{
    __shared__ __align__(16) _Float16 zAh[12 * 144];   // z hi, K=96 (72+pad)
    __shared__ __align__(16) _Float16 hAh[32 * 144];   // h hi, K=256
    __shared__ __align__(16) float red[16][16][20];    // [wv][col lm][row+pad]
    __shared__ __align__(16) float ush[6][16][8];      // interp u per stage/row

    const int tid = threadIdx.x;
    const int wv  = tid >> 6;        // wave 0..15
    const int l   = tid & 63;
    const int lm  = l & 15;
    const int lq  = l >> 4;
    const int blk = blockIdx.x;

    // --- zero z K-pad planes (k=72..95 -> planes 9..11): 216 dwords ---
    if (tid < 216) *(uint32_t*)&zAh[9 * 144 + tid * 2] = 0u;

    // --- GEMM1 B-frags: wave owns N-tile wv (cols wv*16+lm), split hi/lo ---
    const int n1 = wv * 16 + lm;
    const float b1b = b1[n1];
    half8 b1h[3], b1l[3];
#pragma unroll
    for (int c = 0; c < 3; ++c) {
#pragma unroll
        for (int j = 0; j < 8; ++j) {
            const int k = c * 32 + lq * 8 + j;
            const float v = (k < 72) ? W1[k * 256 + n1] : 0.0f;
            const _Float16 hi = (_Float16)v;
            b1h[c][j] = hi;
            b1l[c][j] = (_Float16)(v - (float)hi);
        }
    }

    // --- GEMM2 task (nt = wv&3, kq = wv>>2): B-frags for K-quarter ---
    const int nt = wv & 3;
    const int kq = wv >> 2;
    const int n2 = nt * 16 + lm;
    half8 b2h[2], b2l[2];
#pragma unroll
    for (int cc = 0; cc < 2; ++cc) {
#pragma unroll
        for (int j = 0; j < 8; ++j) {
            const int k = kq * 64 + cc * 32 + lq * 8 + j;
            const float v = W2[k * 64 + n2];
            const _Float16 hi = (_Float16)v;
            b2h[cc][j] = hi;
            b2l[cc][j] = (_Float16)(v - (float)hi);
        }
    }
    const float b2b = b2[n2];

    // --- ODE state: waves 0-3 (kq==0) own cols nt*16+lm, rows lq*4+r ---
    const bool is_st = (wv < 4);
    float xr[4];
    float kfr[5][4];
    if (is_st) {
#pragma unroll
        for (int r = 0; r < 4; ++r) {
            const int gr = blk * 16 + lq * 4 + r;
            xr[r] = x0[gr * 64 + n2];
            out[gr * 3200 + n2] = xr[r];      // t_eval[0]
        }
    }
    __syncthreads();   // pad zeros visible

#pragma unroll 1
    for (int step = 0; step < 196; ++step) {
        const int n = step >> 2;
        const int m = step & 3;
        const float te0 = t_eval[n];
        const float dtc = t_eval[n + 1] - te0;
        const float t   = te0 + dtc * (0.25f * (float)m);
        const float dt  = dtc * 0.25f;

        // --- u prefetch+interp: 768 slots (6 stages x 16 rows x 8 feats) ---
        if (tid < 768) {
            const int s   = tid >> 7;           // wave-uniform
            const int rem = tid & 127;
            const int mr  = rem >> 3, f = rem & 7;
            float cs;
            switch (s) {
                case 0: cs = 0.0f; break;
                case 1: cs = 1.0f / 5.0f; break;
                case 2: cs = 3.0f / 10.0f; break;
                case 3: cs = 4.0f / 5.0f; break;
                case 4: cs = 8.0f / 9.0f; break;
                default: cs = 1.0f; break;
            }
            const float tsv = t + dt * cs;
            int iu = (int)(tsv * 127.0f);       // == searchsorted-1
            iu = iu < 0 ? 0 : (iu > 126 ? 126 : iu);
            const float ta = t_u[iu];
            const float tb = t_u[iu + 1];
            const float wt = (tsv - ta) / (tb - ta);
            const float* ub = &u_batch[(blk * 16 + mr) * 1024 + iu * 8 + f];
            const float u0v = ub[0];
            const float u1v = ub[8];
            ush[s][mr][f] = fmaf(wt, u1v - u0v, u0v);
        }
        __syncthreads();   // B0: ush ready

#pragma unroll
        for (int s = 0; s < 6; ++s) {
            // --- state waves publish z x-part (hi only) ---
            if (is_st) {
#pragma unroll
                for (int r = 0; r < 4; ++r) {
                    float v;
                    if (s == 0)      v = xr[r];
                    else if (s == 1) v = fmaf(dt, kfr[0][r] * (1.0f/5.0f), xr[r]);
                    else if (s == 2) v = fmaf(dt, fmaf(3.0f/40.0f, kfr[0][r], (9.0f/40.0f)*kfr[1][r]), xr[r]);
                    else if (s == 3) v = fmaf(dt, (44.0f/45.0f)*kfr[0][r] + (-56.0f/15.0f)*kfr[1][r]
                                                 + (32.0f/9.0f)*kfr[2][r], xr[r]);
                    else if (s == 4) v = fmaf(dt, (19372.0f/6561.0f)*kfr[0][r] + (-25360.0f/2187.0f)*kfr[1][r]
                                                 + (64448.0f/6561.0f)*kfr[2][r] + (-212.0f/729.0f)*kfr[3][r], xr[r]);
                    else             v = fmaf(dt, (9017.0f/3168.0f)*kfr[0][r] + (-355.0f/33.0f)*kfr[1][r]
                                                 + (46732.0f/5247.0f)*kfr[2][r] + (49.0f/176.0f)*kfr[3][r]
                                                 + (-5103.0f/18656.0f)*kfr[4][r], xr[r]);
                    zAh[(n2 >> 3) * 144 + (lq * 4 + r) * 8 + (n2 & 7)] = (_Float16)v;
                }
            }
            // --- wave 4: z u-part (plane kq=8), dword-packed ---
            if (wv == 4) {
                const int mm = l >> 2;
                const int jj = (l & 3) * 2;
                const _Float16 u0h = (_Float16)ush[s][mm][jj];
                const _Float16 u1h = (_Float16)ush[s][mm][jj + 1];
                uint32_t pk = (uint32_t)*(const uint16_t*)&u0h
                            | ((uint32_t)*(const uint16_t*)&u1h << 16);
                *(uint32_t*)&zAh[8 * 144 + mm * 8 + jj] = pk;
            }
            __syncthreads();   // B1: z ready

            // --- GEMM1: 3 A-reads, 2-term split, 1 N-tile ---
            half8 az[3];
#pragma unroll
            for (int c = 0; c < 3; ++c)
                az[c] = *(const half8*)&zAh[(c * 4 + lq) * 144 + lm * 8];
            f32x4 aHH = {0.f, 0.f, 0.f, 0.f};
            f32x4 aHL = {0.f, 0.f, 0.f, 0.f};
#pragma unroll
            for (int c = 0; c < 3; ++c) {
                aHH = MFMA16(az[c], b1h[c], aHH);
                aHL = MFMA16(az[c], b1l[c], aHL);
            }
            const int kqb = wv * 2 + (lm >> 3);   // h-col>>3 plane
#pragma unroll
            for (int r = 0; r < 4; ++r) {
                const float hv = fast_tanh(aHH[r] + aHL[r] + b1b);
                hAh[kqb * 144 + (lq * 4 + r) * 8 + (lm & 7)] = (_Float16)hv;
            }
            __syncthreads();   // B2: h ready

            // --- GEMM2: K-quarter kq, 2 A-reads, 4 MFMAs, partial to red ---
            f32x4 aP = {0.f, 0.f, 0.f, 0.f};
            f32x4 aQ = {0.f, 0.f, 0.f, 0.f};
#pragma unroll
            for (int cc = 0; cc < 2; ++cc) {
                const half8 ah = *(const half8*)&hAh[(kq * 8 + cc * 4 + lq) * 144 + lm * 8];
                aP = MFMA16(ah, b2h[cc], aP);
                aQ = MFMA16(ah, b2l[cc], aQ);
            }
            const f32x4 psum = aP + aQ;
            *(f32x4*)&red[wv][lm][lq * 4] = psum;
            __syncthreads();   // B3: partials ready

            // --- state waves: reduce 4 K-quarters -> k_s ---
            if (is_st) {
                const f32x4 p0 = *(const f32x4*)&red[nt][lm][lq * 4];
                const f32x4 p1 = *(const f32x4*)&red[nt + 4][lm][lq * 4];
                const f32x4 p2 = *(const f32x4*)&red[nt + 8][lm][lq * 4];
                const f32x4 p3 = *(const f32x4*)&red[nt + 12][lm][lq * 4];
                if (s < 5) {
#pragma unroll
                    for (int r = 0; r < 4; ++r)
                        kfr[s][r] = ((p0[r] + p1[r]) + (p2[r] + p3[r])) + b2b;
                } else {
#pragma unroll
                    for (int r = 0; r < 4; ++r) {
                        const float k6 = ((p0[r] + p1[r]) + (p2[r] + p3[r])) + b2b;
                        xr[r] = fmaf(dt, (35.0f/384.0f)*kfr[0][r] + (500.0f/1113.0f)*kfr[2][r]
                                        + (125.0f/192.0f)*kfr[3][r] + (-2187.0f/6784.0f)*kfr[4][r]
                                        + (11.0f/84.0f)*k6, xr[r]);
                    }
                }
            }
        }

        // --- output every 4th substep ---
        if (is_st && m == 3) {
#pragma unroll
            for (int r = 0; r < 4; ++r)
                out[(blk * 16 + lq * 4 + r) * 3200 + (n + 1) * 64 + n2] = xr[r];
        }
    }
}

extern "C" void kernel_launch(void* const* d_in, const int* in_sizes, int n_in,
                              void* d_out, int out_size, void* d_ws, size_t ws_size,
                              hipStream_t stream) {
    const float* x0      = (const float*)d_in[0];
    const float* t_eval  = (const float*)d_in[1];
    const float* t_u     = (const float*)d_in[2];
    const float* u_batch = (const float*)d_in[3];
    const float* W1      = (const float*)d_in[4];
    const float* b1      = (const float*)d_in[5];
    const float* W2      = (const float*)d_in[6];
    const float* b2      = (const float*)d_in[7];
    float* out = (float*)d_out;

    node_kernel<<<dim3(64), dim3(1024), 0, stream>>>(
        x0, t_eval, t_u, u_batch, W1, b1, W2, b2, out);
}